// Round 3
// baseline (143022.656 us; speedup 1.0000x reference)
//
#include <hip/hip_runtime.h>
#include <cstdint>
#include <cstddef>

// SimpleRNN on MI355X.
// Outputs (fp32, concatenated): out0 output_tensor (512,64,256), out1 input_proj (64,512,1024),
// out2 tot_rnnhid (64,512,1024), out3 tot_output (64,512,256).
// Pipeline: prep (transpose Win/Wout to bf16 in ws, zero rendezvous words) -> input_proj GEMM
//  -> persistent scan (256 WGs = 1/CU, Wr bf16 in VGPR B-frags, per-wave flag sync,
//     y-history bf16 parked in out0/out3 regions) -> output GEMM (reads out2, writes out0/out3).
// R2->R3: removed per-step agent fences; per-wave flags; plain hout. 7.1ms -> 2.47ms scan.
// R3->R4 attempt FAILED (infra timeout). Root cause: each WG decided L2-vs-agent sync mode
//  INDEPENDENTLY -> any timeout => mixed protocol => flags invisible => per-step watchdog
//  => minute-long kernel. Also prep zeroed rendezvous words with PLAIN stores (dirty L2)
//  while scan RMW'd them with agent atomics (L3) -> writeback clobber.
// R4->R5 (this round): same XCD-local-L2 sync theory, divergence-free decision:
//  - rendezvous words touched ONLY by agent atomics (prep zeroes atomically);
//  - each WG ORs (1<<XCC_ID) into its group mask, vmcnt(0), then count++;
//  - WG 0 alone decides (count==256 && all 16 group masks single-bit) and publishes
//    verdict (1=L2-local sync, 2=agent sync); all WGs poll the single verdict word;
//  - per-step watchdog is sticky (gaveup -> race onward, visible absmax fail, no timeout).
//  L2 mode: producers plain write-through stores (y, flags) -> XCD L2 (~85ns RT);
//  consumers sc0 loads (bypass L1, hit L2). Agent mode: R3 protocol (passed, 2.47ms).
//  Release path: y stores -> vmcnt(0) -> flag -> hout (hout visibility = kernel boundary).

typedef short bf16x8 __attribute__((ext_vector_type(8)));
typedef float f32x4  __attribute__((ext_vector_type(4)));

#define O1_OFF 8388608UL
#define O2_OFF 41943040UL
#define O3_OFF 75497472UL

__device__ __forceinline__ unsigned short f2bf(float f) {
    unsigned u = __float_as_uint(f);
    u += 0x7FFFu + ((u >> 16) & 1u);   // round-to-nearest-even
    return (unsigned short)(u >> 16);
}

// tanh(x) = 1 - 2/(1+exp2(2*log2(e)*x)); ~1e-6 rel err, far below bf16 quantum.
// Saturates correctly: x->+inf => 1, x->-inf => -1.
__device__ __forceinline__ float fast_tanh(float x) {
    float e = __builtin_amdgcn_exp2f(2.8853900817779268f * x);
    return 1.0f - 2.0f * __builtin_amdgcn_rcpf(e + 1.0f);
}

// L1-bypassing load, served by the XCD-local L2 (write-through L1 makes plain stores
// from other CUs on the same XCD visible here).
__device__ __forceinline__ int ld_sc0(const int* p) {
    int v;
    asm volatile("global_load_dword %0, %1, off sc0\n\t"
                 "s_waitcnt vmcnt(0)"
                 : "=v"(v) : "v"(p) : "memory");
    return v;
}

// ---------------------------------------------------------------------------
// Prep: Win (256k x 1024n) -> winT bf16 [1024n][256k];  Wout (1024k x 256n) -> woutT bf16 [256n][1024k]
// Also zeroes the rendezvous words via AGENT ATOMICS (no dirty-L2 clobber hazard).
// ---------------------------------------------------------------------------
__global__ void prep_transpose(const float* __restrict__ Win, const float* __restrict__ Wout,
                               unsigned short* __restrict__ winT, unsigned short* __restrict__ woutT,
                               int* __restrict__ syncw)
{
    __shared__ float tbuf[64 * 65];
    const int tid = threadIdx.x;
    const int bx = blockIdx.x;
    if (bx == 0 && tid < 96)
        __hip_atomic_store(syncw + tid, 0, __ATOMIC_RELAXED, __HIP_MEMORY_SCOPE_AGENT);
    const float* src; unsigned short* dst; int k0, n0, srcld, dstld;
    if (bx < 64) { int tk = bx & 3, tn = bx >> 2; k0 = tk * 64; n0 = tn * 64; src = Win;  srcld = 1024; dst = winT;  dstld = 256; }
    else         { int b2 = bx - 64; int tk = b2 >> 2, tn = b2 & 3; k0 = tk * 64; n0 = tn * 64; src = Wout; srcld = 256;  dst = woutT; dstld = 1024; }

    for (int it = 0; it < 16; ++it) {
        int flat = it * 256 + tid;
        int k = flat >> 6, nn = flat & 63;
        tbuf[k * 65 + nn] = src[(size_t)(k0 + k) * srcld + n0 + nn];
    }
    __syncthreads();
    int* d32 = (int*)dst;
    for (int it = 0; it < 8; ++it) {
        int flat = it * 256 + tid;            // 0..2047
        int nn = flat >> 5, kd = flat & 31;   // kd = k-pair index
        float v0 = tbuf[(2 * kd) * 65 + nn];
        float v1 = tbuf[(2 * kd + 1) * 65 + nn];
        d32[(size_t)(n0 + nn) * (dstld / 2) + (k0 / 2) + kd] = (int)(f2bf(v0) | ((unsigned)f2bf(v1) << 16));
    }
}

// ---------------------------------------------------------------------------
// Phase A: input_proj = x(32768r x 256k) @ Win(256k x 1024n), out1[(b*512+t)*1024+n], r = t*64+b
// ---------------------------------------------------------------------------
__launch_bounds__(256, 1)
__global__ void input_proj_kernel(const float* __restrict__ x, const unsigned short* __restrict__ winT,
                                  float* __restrict__ ip)
{
    extern __shared__ short lds[];
    short* win_s = lds;             // [256 n][264] bf16
    short* x_s   = lds + 256 * 264; // [32 m][264] bf16
    const int tid = threadIdx.x;
    const int lane = tid & 63, wv = tid >> 6;
    const int nslice = blockIdx.x & 3;
    const int wgm = blockIdx.x >> 2;
    const int n0 = nslice * 256;
    const int n = lane & 15, q = lane >> 4;

    { // stage WinT slice, coalesced + conflict-free
        const int* src = (const int*)winT;   // [1024][128 dwords]
        int* dstl = (int*)win_s;             // pitch 132 dwords
        for (int it = 0; it < 128; ++it) {
            int flat = it * 256 + tid;
            int nn = flat >> 7, kd = flat & 127;
            dstl[nn * 132 + kd] = src[(size_t)(n0 + nn) * 128 + kd];
        }
    }
    __syncthreads();

    const int msub = (wv & 1) * 16;
    const int ntbase = (wv >> 1) * 8;

    for (int i = 0; i < 16; ++i) {
        int mt = wgm * 16 + i;
        int r0 = mt * 32;
        { // stage x tile 32x256 fp32 -> bf16
            for (int it = 0; it < 16; ++it) {
                int flat = it * 256 + tid;     // 0..4095
                int rr = flat >> 7, kp = flat & 127;
                const float* xp = x + (size_t)(r0 + rr) * 256 + kp * 2;
                ((int*)x_s)[rr * 132 + kp] = (int)(f2bf(xp[0]) | ((unsigned)f2bf(xp[1]) << 16));
            }
        }
        __syncthreads();

        f32x4 acc[8] = {};
#pragma unroll
        for (int kc = 0; kc < 8; ++kc) {
            bf16x8 af = *(const bf16x8*)(x_s + (msub + n) * 264 + kc * 32 + q * 8);
#pragma unroll
            for (int u = 0; u < 8; ++u) {
                bf16x8 bfv = *(const bf16x8*)(win_s + ((ntbase + u) * 16 + n) * 264 + kc * 32 + q * 8);
                acc[u] = __builtin_amdgcn_mfma_f32_16x16x32_bf16(af, bfv, acc[u], 0, 0, 0);
            }
        }
#pragma unroll
        for (int u = 0; u < 8; ++u) {
            int ncol = n0 + (ntbase + u) * 16 + n;
#pragma unroll
            for (int rr = 0; rr < 4; ++rr) {
                int R = r0 + msub + q * 4 + rr;
                int t = R >> 6, b = R & 63;
                ip[((size_t)b * 512 + t) * 1024 + ncol] = acc[u][rr];
            }
        }
        __syncthreads();
    }
}

// ---------------------------------------------------------------------------
// Persistent scan. 256 WGs x 256 thr (plain launch; 1 WG/CU => all co-resident).
// group g = 4 batches, 16 WGs/group x 64 cols; group g is XCD-local IF bx%8 == XCC_ID
// (verified at runtime via the mask rendezvous; single decider => no mode divergence).
// ---------------------------------------------------------------------------
__launch_bounds__(256, 1)
__global__ void rnn_scan(const float* __restrict__ Wr, const float* __restrict__ bias,
                         const float* __restrict__ ip, float* __restrict__ hout,
                         char* ybase0, char* ybase3, int* flags, int* syncw)
{
    __shared__ short y_lds[4 * 1032];
    __shared__ float ip_w0[2][64];     // wave1-proxied ip slice for wave0, parity dbuf
    __shared__ int mode_lds;
    const int tid = threadIdx.x;
    const int lane = tid & 63;
    const int wv = tid >> 6;
    const int bx = blockIdx.x;
    const int j = bx >> 3;              // 0..31
    const int g = (bx & 7) + 8 * (j & 1);   // group 0..15
    const int w = j >> 1;               // slice 0..15
    const int b0 = g * 4;
    const int colbase = w * 64 + wv * 16;
    const int n = lane & 15;            // col within tile; also A-frag row index
    const int q = lane >> 4;
    const int col = colbase + n;

    int* regw    = syncw;        // count of registered WGs
    int* verdict = syncw + 32;   // 0=undecided, 1=L2-local, 2=agent
    int* masks   = syncw + 64;   // 16 per-group XCD bitmasks

    // --- rendezvous phase 1: publish this WG's physical XCD into its group mask ---
    if (tid == 0) {
        int myxcd;
        asm volatile("s_getreg_b32 %0, hwreg(HW_REG_XCC_ID)" : "=s"(myxcd));
        __hip_atomic_fetch_or(masks + g, 1 << (myxcd & 15), __ATOMIC_RELAXED, __HIP_MEMORY_SCOPE_AGENT);
        asm volatile("s_waitcnt vmcnt(0)" ::: "memory");   // mask OR done before count bump
        __hip_atomic_fetch_add(regw, 1, __ATOMIC_RELAXED, __HIP_MEMORY_SCOPE_AGENT);
    }

    // Load Wr B-frags (overlaps rendezvous): lane holds Wr[kc*32+q*8+jj][col], bf16
    bf16x8 wrf[32];
#pragma unroll
    for (int kc = 0; kc < 32; ++kc) {
        int kbase = kc * 32 + q * 8;
        union { bf16x8 v; unsigned short u[8]; } tmp;
#pragma unroll
        for (int jj = 0; jj < 8; ++jj)
            tmp.u[jj] = f2bf(Wr[(size_t)(kbase + jj) * 1024 + col]);
        wrf[kc] = tmp.v;
    }
    const float biasv = bias[col];

    // --- rendezvous phase 2: WG 0 alone decides; everyone polls the verdict ---
    if (bx == 0 && tid == 0) {
        int spins = 0, cnt = 0;
        while (true) {
            cnt = __hip_atomic_load(regw, __ATOMIC_RELAXED, __HIP_MEMORY_SCOPE_AGENT);
            if (cnt >= 256) break;
            if (__builtin_expect(++spins > (1 << 20), 0)) break;
            __builtin_amdgcn_s_sleep(2);
        }
        asm volatile("" ::: "memory");
        int ok = (cnt >= 256) ? 1 : 0;
        for (int i = 0; i < 16; ++i) {
            int m = __hip_atomic_load(masks + i, __ATOMIC_RELAXED, __HIP_MEMORY_SCOPE_AGENT);
            if (m == 0 || (m & (m - 1)) != 0) ok = 0;   // group spans XCDs (or missing)
        }
        __hip_atomic_store(verdict, ok ? 1 : 2, __ATOMIC_RELAXED, __HIP_MEMORY_SCOPE_AGENT);
    }
    if (tid == 0) {
        int spins = 0, v = 0;
        while (true) {
            v = __hip_atomic_load(verdict, __ATOMIC_RELAXED, __HIP_MEMORY_SCOPE_AGENT);
            if (v != 0) break;
            if (__builtin_expect(++spins > (1 << 22), 0)) { v = 2; break; }  // practically unreachable
            __builtin_amdgcn_s_sleep(2);
        }
        mode_lds = v;
    }
    __syncthreads();
    const bool l2m = (mode_lds == 1);

    float h[4] = {0.f, 0.f, 0.f, 0.f};
    int gaveup = 0;
    // per-wave flags: index (g*64 + w*4 + wv), spaced 16B. 16 groups * 64 * 16B = 16KB.
    int* wflag = flags + ((g * 64 + w * 4 + wv) << 2);
    int* pflag = flags + ((g * 64 + lane) << 2);   // wave0: lane -> (w=lane>>2, wv=lane&3)

    for (int t = 0; t < 512; ++t) {
        // ip prefetch: waves 1-3 load their own slice (nt: single-use stream, keep L2 for y).
        // wave0 loads NOTHING here so its vmem queue holds only poll loads (+ last hout).
        float ipv[4] = {0.f, 0.f, 0.f, 0.f};
        if (wv != 0 && lane < 16) {
#pragma unroll
            for (int rr = 0; rr < 4; ++rr)
                ipv[rr] = __builtin_nontemporal_load(ip + ((size_t)(b0 + rr) * 512 + t) * 1024 + col);
        }
        // wave1 additionally proxies wave0's slice (col for wv==0 is w*64+n) into LDS
        if (wv == 1 && lane < 16) {
            float w0v[4];
#pragma unroll
            for (int rr = 0; rr < 4; ++rr)
                w0v[rr] = __builtin_nontemporal_load(ip + ((size_t)(b0 + rr) * 512 + t) * 1024 + (w * 64 + n));
#pragma unroll
            for (int rr = 0; rr < 4; ++rr)
                ip_w0[t & 1][rr * 16 + n] = w0v[rr];
        }

        f32x4 acc0 = {0.f, 0.f, 0.f, 0.f}, acc1 = {0.f, 0.f, 0.f, 0.f};
        if (t > 0) {
            // wave 0 waits for all 64 per-wave producers of y_{t-1}; watchdog is STICKY:
            // one trip -> race onward (fast, visibly-wrong finish; never a timeout)
            if (wv == 0 && !gaveup) {
                int spins = 0;
                while (true) {
                    int v = l2m ? ld_sc0(pflag)
                                : __hip_atomic_load(pflag, __ATOMIC_RELAXED, __HIP_MEMORY_SCOPE_AGENT);
                    if (__all(v >= t)) break;
                    if (__builtin_expect(++spins > (1 << 20), 0)) { gaveup = 1; break; }
                    __builtin_amdgcn_s_sleep(1);
                }
            }
            asm volatile("" ::: "memory");
            __syncthreads();   // releases waves 1-3; orders wave1's ip_w0 write before reads

            // stage y_{t-1} rows b0..b0+3 (4 x 1024 bf16 = 2048 dwords) into LDS
            const int* ysrc = (const int*)((t - 1) < 256 ? (ybase0 + (size_t)(t - 1) * 131072)
                                                         : (ybase3 + (size_t)(t - 1 - 256) * 131072));
            {
                int r = tid >> 6;       // 0..3
                int c0 = tid & 63;
                const int* bsrc = ysrc + (b0 + r) * 512 + c0;
                int* yl = (int*)y_lds + r * 516 + c0;
                if (l2m) {
                    int v0, v1, v2, v3, v4, v5, v6, v7;
                    asm volatile(
                        "global_load_dword %0, %8, off sc0\n\t"
                        "global_load_dword %1, %8, off offset:256 sc0\n\t"
                        "global_load_dword %2, %8, off offset:512 sc0\n\t"
                        "global_load_dword %3, %8, off offset:768 sc0\n\t"
                        "global_load_dword %4, %8, off offset:1024 sc0\n\t"
                        "global_load_dword %5, %8, off offset:1280 sc0\n\t"
                        "global_load_dword %6, %8, off offset:1536 sc0\n\t"
                        "global_load_dword %7, %8, off offset:1792 sc0\n\t"
                        "s_waitcnt vmcnt(0)"
                        : "=&v"(v0), "=&v"(v1), "=&v"(v2), "=&v"(v3),
                          "=&v"(v4), "=&v"(v5), "=&v"(v6), "=&v"(v7)
                        : "v"(bsrc) : "memory");
                    yl[0] = v0; yl[64] = v1; yl[128] = v2; yl[192] = v3;
                    yl[256] = v4; yl[320] = v5; yl[384] = v6; yl[448] = v7;
                } else {
#pragma unroll
                    for (int it = 0; it < 8; ++it)
                        yl[it * 64] = __hip_atomic_load(bsrc + it * 64, __ATOMIC_RELAXED, __HIP_MEMORY_SCOPE_AGENT);
                }
            }
            __syncthreads();

            // MFMA over K=1024: A rows 0-3 = y batches, rows 4-15 zero
#pragma unroll
            for (int kc = 0; kc < 32; kc += 2) {
                bf16x8 a0, a1;
                if (n < 4) {
                    a0 = *(const bf16x8*)(y_lds + n * 1032 + kc * 32 + q * 8);
                    a1 = *(const bf16x8*)(y_lds + n * 1032 + (kc + 1) * 32 + q * 8);
                } else { a0 = (bf16x8)0; a1 = (bf16x8)0; }
                acc0 = __builtin_amdgcn_mfma_f32_16x16x32_bf16(a0, wrf[kc],     acc0, 0, 0, 0);
                acc1 = __builtin_amdgcn_mfma_f32_16x16x32_bf16(a1, wrf[kc + 1], acc1, 0, 0, 0);
            }
        } else {
            __syncthreads();   // t==0: order wave1's ip_w0 write before wave0's read
        }

        // wave0's ipv comes from the LDS proxy (parity dbuf => no cross-step race)
        if (wv == 0 && lane < 16) {
#pragma unroll
            for (int rr = 0; rr < 4; ++rr)
                ipv[rr] = ip_w0[t & 1][rr * 16 + n];
        }

        // h update (lanes>=16 compute phantom rows; never stored, A-rows forced zero so harmless)
#pragma unroll
        for (int rr = 0; rr < 4; ++rr) {
            float rv = acc0[rr] + acc1[rr];
            h[rr] = 0.95f * h[rr] + 0.05f * (rv + ipv[rr] + biasv);
        }

        // release path: y stores -> vmcnt(0) -> flag -> hout (hout ordered by kernel boundary)
        char* ydst = (t < 256) ? (ybase0 + (size_t)t * 131072) : (ybase3 + (size_t)(t - 256) * 131072);
        unsigned short* yp = (unsigned short*)ydst;
        if (lane < 16) {
#pragma unroll
            for (int rr = 0; rr < 4; ++rr) {
                unsigned short yb = f2bf(fast_tanh(h[rr]));
                if (l2m) {
                    *(volatile unsigned short*)(yp + (b0 + rr) * 1024 + col) = yb;   // write-through -> XCD L2
                } else {
                    __hip_atomic_store(yp + (b0 + rr) * 1024 + col, yb,
                                       __ATOMIC_RELAXED, __HIP_MEMORY_SCOPE_AGENT);
                }
            }
        }
        asm volatile("s_waitcnt vmcnt(0)" ::: "memory");   // THIS wave's y stores committed
        if (lane == 0) {
            if (l2m) *(volatile int*)wflag = t + 1;                                  // write-through -> XCD L2
            else __hip_atomic_store(wflag, t + 1, __ATOMIC_RELAXED, __HIP_MEMORY_SCOPE_AGENT);
        }
        if (lane < 16) {
#pragma unroll
            for (int rr = 0; rr < 4; ++rr)
                __builtin_nontemporal_store(h[rr], hout + ((size_t)(b0 + rr) * 512 + t) * 1024 + col);
        }
    }
}

// ---------------------------------------------------------------------------
// Phase C: rnn_out = tanh(out2) (32768r x 1024k) @ Wout -> out3[R*256+n] and out0[(t*64+b)*256+n]
// ---------------------------------------------------------------------------
__launch_bounds__(256, 1)
__global__ void out_proj_kernel(const float* __restrict__ h, const unsigned short* __restrict__ woutT,
                                float* __restrict__ out0, float* __restrict__ out3)
{
    extern __shared__ short lds[];      // [256 n][136] bf16 per k-block
    const int tid = threadIdx.x;
    const int lane = tid & 63, wv = tid >> 6;
    const int R0 = blockIdx.x * 64;
    const int n = lane & 15, q = lane >> 4;
    f32x4 acc[16] = {};

    for (int kb = 0; kb < 8; ++kb) {
        { // stage WoutT block, coalesced + conflict-free
            const int* src = (const int*)woutT;   // [256][512 dwords]
            int* dstl = (int*)lds;                // pitch 68 dwords
#pragma unroll
            for (int it = 0; it < 64; ++it) {
                int flat = it * 256 + tid;
                int nn = flat >> 6, kd = flat & 63;
                dstl[nn * 68 + kd] = src[(size_t)nn * 512 + kb * 64 + kd];
            }
        }
        __syncthreads();

        const int row = R0 + wv * 16 + n;
#pragma unroll
        for (int kc = 0; kc < 4; ++kc) {
            int k = kb * 128 + kc * 32 + q * 8;
            const float* hp = h + (size_t)row * 1024 + k;
            union { bf16x8 v; unsigned short u[8]; } af;
#pragma unroll
            for (int jj = 0; jj < 8; ++jj) af.u[jj] = f2bf(fast_tanh(hp[jj]));
#pragma unroll
            for (int u2 = 0; u2 < 16; ++u2) {
                bf16x8 bfv = *(const bf16x8*)(lds + (u2 * 16 + n) * 136 + kc * 32 + q * 8);
                acc[u2] = __builtin_amdgcn_mfma_f32_16x16x32_bf16(af.v, bfv, acc[u2], 0, 0, 0);
            }
        }
        __syncthreads();
    }
#pragma unroll
    for (int u2 = 0; u2 < 16; ++u2) {
        int ncol = u2 * 16 + n;
#pragma unroll
        for (int rr = 0; rr < 4; ++rr) {
            int R = R0 + wv * 16 + q * 4 + rr;
            int b = R >> 9, t = R & 511;
            float v = acc[u2][rr];
            out3[(size_t)R * 256 + ncol] = v;
            out0[((size_t)t * 64 + b) * 256 + ncol] = v;
        }
    }
}

// ---------------------------------------------------------------------------
extern "C" void kernel_launch(void* const* d_in, const int* in_sizes, int n_in,
                              void* d_out, int out_size, void* d_ws, size_t ws_size,
                              hipStream_t stream)
{
    const float* x    = (const float*)d_in[0];
    const float* Win  = (const float*)d_in[1];
    const float* Wr   = (const float*)d_in[2];
    const float* bias = (const float*)d_in[3];
    const float* Wout = (const float*)d_in[4];
    float* out = (float*)d_out;
    float* o0 = out;
    float* o1 = out + O1_OFF;
    float* o2 = out + O2_OFF;
    float* o3 = out + O3_OFF;

    // ws layout: [0,16K) per-wave flags (poison 0xAA.. reads as negative => safe),
    // [16K,16K+512) rendezvous words (atomically zeroed by prep), [16896,+512K) winT, then woutT
    int* flags = (int*)d_ws;
    int* syncw = (int*)((char*)d_ws + 16384);
    unsigned short* winT  = (unsigned short*)((char*)d_ws + 16896);
    unsigned short* woutT = (unsigned short*)((char*)d_ws + 16896 + 524288);

    hipFuncSetAttribute((const void*)input_proj_kernel, hipFuncAttributeMaxDynamicSharedMemorySize, 152064);
    hipFuncSetAttribute((const void*)out_proj_kernel,   hipFuncAttributeMaxDynamicSharedMemorySize, 69632);

    hipLaunchKernelGGL(prep_transpose, dim3(128), dim3(256), 0, stream, Win, Wout, winT, woutT, syncw);
    hipLaunchKernelGGL(input_proj_kernel, dim3(256), dim3(256), 152064, stream, x, winT, o1);

    hipLaunchKernelGGL(rnn_scan, dim3(256), dim3(256), 0, stream,
                       Wr, bias, o1, o2, (char*)o0, (char*)o3, flags, syncw);

    hipLaunchKernelGGL(out_proj_kernel, dim3(512), dim3(256), 69632, stream, o2, woutT, o0, o3);
}

// Round 4
// 2434.158 us; speedup vs baseline: 58.7565x; 58.7565x over previous
//
#include <hip/hip_runtime.h>
#include <cstdint>
#include <cstddef>

// SimpleRNN on MI355X.
// Outputs (fp32, concatenated): out0 output_tensor (512,64,256), out1 input_proj (64,512,1024),
// out2 tot_rnnhid (64,512,1024), out3 tot_output (64,512,256).
// Pipeline: poison (fill out0/out3 y-regions with bf16 +inf sentinel) -> prep (transpose
//  Win/Wout to bf16 in ws) -> input_proj GEMM (writes out1) -> persistent scan (256 WGs =
//  1/CU, Wr bf16 in VGPR B-frags, DATA-AS-FLAG sync, y-history bf16 in out0/out3 regions)
//  -> output GEMM (reads out2, overwrites out0/out3 with final values).
// History:
//  R2->R3: removed per-step agent fences; per-wave flags; plain hout. 7.1ms -> 2.47ms scan.
//  R4/R5 (XCD-local L2 sync via plain-store + sc0-load): FAILED. R5 run = 255ms/dispatch =
//   exactly one sticky 2^20-spin watchdog trip then an unsynchronized (luckily-correct) race.
//   Mask rendezvous PASSED (bx%8==XCC_ID confirmed) but sc0/volatile flag never became
//   visible -> assumed gfx950 cache-flag semantics are wrong; L2-local sync abandoned.
//  R6 (this round): back to PROVEN R1 primitives (relaxed agent atomics), restructured
//   protocol: DATA-AS-FLAG. y buffers are step-indexed (write-once, no ABA) and tanh output
//   can never be bf16 0x7F80 (+inf), so consumers poll the y dwords themselves until both
//   halves != sentinel. Producers fire y-stores and NEVER wait (no ack RT, no flag store);
//   consumer detect == data arrival. Removes 2 of 3 serial L3 round-trips per step.
//   Sticky per-thread watchdog: a trip feeds +inf -> NaN absmax (visible), never a hang.

typedef short bf16x8 __attribute__((ext_vector_type(8)));
typedef float f32x4  __attribute__((ext_vector_type(4)));
typedef int   int4v  __attribute__((ext_vector_type(4)));

#define O1_OFF 8388608UL
#define O2_OFF 41943040UL
#define O3_OFF 75497472UL

#define SENT 0x7F80            // bf16 +inf: impossible for tanh output
#define SENT2 0x7F807F80

__device__ __forceinline__ unsigned short f2bf(float f) {
    unsigned u = __float_as_uint(f);
    u += 0x7FFFu + ((u >> 16) & 1u);   // round-to-nearest-even
    return (unsigned short)(u >> 16);
}

// tanh(x) = 1 - 2/(1+exp2(2*log2(e)*x)); ~1e-6 rel err, far below bf16 quantum.
// Saturates correctly: x->+inf => 1, x->-inf => -1. (Ran correct in R5: absmax unchanged.)
__device__ __forceinline__ float fast_tanh(float x) {
    float e = __builtin_amdgcn_exp2f(2.8853900817779268f * x);
    return 1.0f - 2.0f * __builtin_amdgcn_rcpf(e + 1.0f);
}

// ---------------------------------------------------------------------------
// Poison: fill out0 and out3 (each 33.55MB, exactly the 256-step y regions) with
// the bf16 +inf sentinel. 2048 WGs x 256 thr x 4 x 16B x 2 regions. Plain nt
// stores; visibility to the scan via the kernel-end implicit release (stream order).
// ---------------------------------------------------------------------------
__global__ void poison_y(int* __restrict__ o0, int* __restrict__ o3)
{
    const int flat = blockIdx.x * 256 + threadIdx.x;        // 0..524287
    int4v p = {SENT2, SENT2, SENT2, SENT2};
#pragma unroll
    for (int c = 0; c < 4; ++c) {
        size_t off = (size_t)c * 2097152 + (size_t)flat * 4;   // dword offset
        __builtin_nontemporal_store(p, (int4v*)(o0 + off));
        __builtin_nontemporal_store(p, (int4v*)(o3 + off));
    }
}

// ---------------------------------------------------------------------------
// Prep: Win (256k x 1024n) -> winT bf16 [1024n][256k];  Wout (1024k x 256n) -> woutT bf16 [256n][1024k]
// ---------------------------------------------------------------------------
__global__ void prep_transpose(const float* __restrict__ Win, const float* __restrict__ Wout,
                               unsigned short* __restrict__ winT, unsigned short* __restrict__ woutT)
{
    __shared__ float tbuf[64 * 65];
    const int tid = threadIdx.x;
    const int bx = blockIdx.x;
    const float* src; unsigned short* dst; int k0, n0, srcld, dstld;
    if (bx < 64) { int tk = bx & 3, tn = bx >> 2; k0 = tk * 64; n0 = tn * 64; src = Win;  srcld = 1024; dst = winT;  dstld = 256; }
    else         { int b2 = bx - 64; int tk = b2 >> 2, tn = b2 & 3; k0 = tk * 64; n0 = tn * 64; src = Wout; srcld = 256;  dst = woutT; dstld = 1024; }

    for (int it = 0; it < 16; ++it) {
        int flat = it * 256 + tid;
        int k = flat >> 6, nn = flat & 63;
        tbuf[k * 65 + nn] = src[(size_t)(k0 + k) * srcld + n0 + nn];
    }
    __syncthreads();
    int* d32 = (int*)dst;
    for (int it = 0; it < 8; ++it) {
        int flat = it * 256 + tid;            // 0..2047
        int nn = flat >> 5, kd = flat & 31;   // kd = k-pair index
        float v0 = tbuf[(2 * kd) * 65 + nn];
        float v1 = tbuf[(2 * kd + 1) * 65 + nn];
        d32[(size_t)(n0 + nn) * (dstld / 2) + (k0 / 2) + kd] = (int)(f2bf(v0) | ((unsigned)f2bf(v1) << 16));
    }
}

// ---------------------------------------------------------------------------
// Phase A: input_proj = x(32768r x 256k) @ Win(256k x 1024n), out1[(b*512+t)*1024+n], r = t*64+b
// ---------------------------------------------------------------------------
__launch_bounds__(256, 1)
__global__ void input_proj_kernel(const float* __restrict__ x, const unsigned short* __restrict__ winT,
                                  float* __restrict__ ip)
{
    extern __shared__ short lds[];
    short* win_s = lds;             // [256 n][264] bf16
    short* x_s   = lds + 256 * 264; // [32 m][264] bf16
    const int tid = threadIdx.x;
    const int lane = tid & 63, wv = tid >> 6;
    const int nslice = blockIdx.x & 3;
    const int wgm = blockIdx.x >> 2;
    const int n0 = nslice * 256;
    const int n = lane & 15, q = lane >> 4;

    { // stage WinT slice, coalesced + conflict-free
        const int* src = (const int*)winT;   // [1024][128 dwords]
        int* dstl = (int*)win_s;             // pitch 132 dwords
        for (int it = 0; it < 128; ++it) {
            int flat = it * 256 + tid;
            int nn = flat >> 7, kd = flat & 127;
            dstl[nn * 132 + kd] = src[(size_t)(n0 + nn) * 128 + kd];
        }
    }
    __syncthreads();

    const int msub = (wv & 1) * 16;
    const int ntbase = (wv >> 1) * 8;

    for (int i = 0; i < 16; ++i) {
        int mt = wgm * 16 + i;
        int r0 = mt * 32;
        { // stage x tile 32x256 fp32 -> bf16
            for (int it = 0; it < 16; ++it) {
                int flat = it * 256 + tid;     // 0..4095
                int rr = flat >> 7, kp = flat & 127;
                const float* xp = x + (size_t)(r0 + rr) * 256 + kp * 2;
                ((int*)x_s)[rr * 132 + kp] = (int)(f2bf(xp[0]) | ((unsigned)f2bf(xp[1]) << 16));
            }
        }
        __syncthreads();

        f32x4 acc[8] = {};
#pragma unroll
        for (int kc = 0; kc < 8; ++kc) {
            bf16x8 af = *(const bf16x8*)(x_s + (msub + n) * 264 + kc * 32 + q * 8);
#pragma unroll
            for (int u = 0; u < 8; ++u) {
                bf16x8 bfv = *(const bf16x8*)(win_s + ((ntbase + u) * 16 + n) * 264 + kc * 32 + q * 8);
                acc[u] = __builtin_amdgcn_mfma_f32_16x16x32_bf16(af, bfv, acc[u], 0, 0, 0);
            }
        }
#pragma unroll
        for (int u = 0; u < 8; ++u) {
            int ncol = n0 + (ntbase + u) * 16 + n;
#pragma unroll
            for (int rr = 0; rr < 4; ++rr) {
                int R = r0 + msub + q * 4 + rr;
                int t = R >> 6, b = R & 63;
                ip[((size_t)b * 512 + t) * 1024 + ncol] = acc[u][rr];
            }
        }
        __syncthreads();
    }
}

// ---------------------------------------------------------------------------
// Persistent scan. 256 WGs x 256 thr (plain launch; 1 WG/CU => all co-resident).
// group g = 4 batches, 16 WGs/group x 64 cols. Wave = 16 cols; Wr bf16 B-frags in VGPRs.
// DATA-AS-FLAG: per step, each of the 256 threads stages 8 y-dwords and polls its own
// still-sentinel dwords until both bf16 halves != 0x7F80 (agent-atomic loads, same
// primitive R1 proved). Producers fire 2B agent-atomic y-stores and never wait.
// ---------------------------------------------------------------------------
__launch_bounds__(256, 1)
__global__ void rnn_scan(const float* __restrict__ Wr, const float* __restrict__ bias,
                         const float* __restrict__ ip, float* __restrict__ hout,
                         char* ybase0, char* ybase3)
{
    __shared__ short y_lds[4 * 1032];
    const int tid = threadIdx.x;
    const int lane = tid & 63;
    const int bx = blockIdx.x;
    const int j = bx >> 3;                  // 0..31
    const int g = (bx & 7) + 8 * (j & 1);   // group 0..15 (XCD-affine: harmless locality)
    const int w = j >> 1;                   // slice 0..15
    const int b0 = g * 4;
    const int colbase = w * 64 + (tid >> 6) * 16;
    const int n = lane & 15;                // col within tile; also A-frag row index
    const int q = lane >> 4;
    const int col = colbase + n;

    // Load Wr B-frags: lane holds Wr[kc*32+q*8+jj][col], bf16
    bf16x8 wrf[32];
#pragma unroll
    for (int kc = 0; kc < 32; ++kc) {
        int kbase = kc * 32 + q * 8;
        union { bf16x8 v; unsigned short u[8]; } tmp;
#pragma unroll
        for (int jj = 0; jj < 8; ++jj)
            tmp.u[jj] = f2bf(Wr[(size_t)(kbase + jj) * 1024 + col]);
        wrf[kc] = tmp.v;
    }
    const float biasv = bias[col];

    float h[4] = {0.f, 0.f, 0.f, 0.f};
    int gaveup = 0;
    const int r = tid >> 6;       // staging row 0..3
    const int c0 = tid & 63;      // staging col base (dwords)

    for (int t = 0; t < 512; ++t) {
        // ip prefetch for this step (lanes 0-15 hold batches 0-3 in regs, C-frag layout);
        // nt: single-use stream. Issued before the poll so latency overlaps detection.
        float ipv[4] = {0.f, 0.f, 0.f, 0.f};
        if (lane < 16) {
#pragma unroll
            for (int rr = 0; rr < 4; ++rr)
                ipv[rr] = __builtin_nontemporal_load(ip + ((size_t)(b0 + rr) * 512 + t) * 1024 + col);
        }

        f32x4 acc0 = {0.f, 0.f, 0.f, 0.f}, acc1 = {0.f, 0.f, 0.f, 0.f};
        if (t > 0) {
            // stage y_{t-1} rows b0..b0+3 into LDS, polling until valid (data IS the flag).
            const int* ysrc = (const int*)((t - 1) < 256 ? (ybase0 + (size_t)(t - 1) * 131072)
                                                         : (ybase3 + (size_t)(t - 1 - 256) * 131072));
            const int* bsrc = ysrc + (b0 + r) * 512 + c0;
            int* yl = (int*)y_lds + r * 516 + c0;
            int vals[8];
            if (!gaveup) {
                unsigned pend = 0xFFu;
                int spins = 0;
                while (true) {
#pragma unroll
                    for (int it = 0; it < 8; ++it)
                        if (pend & (1u << it))
                            vals[it] = __hip_atomic_load(bsrc + it * 64, __ATOMIC_RELAXED, __HIP_MEMORY_SCOPE_AGENT);
#pragma unroll
                    for (int it = 0; it < 8; ++it)
                        if (pend & (1u << it)) {
                            int v = vals[it];
                            if ((v & 0xFFFF) != SENT && ((v >> 16) & 0xFFFF) != SENT)
                                pend &= ~(1u << it);
                        }
                    if (pend == 0) break;
                    if (__builtin_expect(++spins > (1 << 16), 0)) { gaveup = 1; break; }
                    __builtin_amdgcn_s_sleep(1);
                }
            } else {
#pragma unroll
                for (int it = 0; it < 8; ++it)
                    vals[it] = __hip_atomic_load(bsrc + it * 64, __ATOMIC_RELAXED, __HIP_MEMORY_SCOPE_AGENT);
            }
#pragma unroll
            for (int it = 0; it < 8; ++it)
                yl[it * 64] = vals[it];
            __syncthreads();

            // MFMA over K=1024: A rows 0-3 = y batches, rows 4-15 zero
#pragma unroll
            for (int kc = 0; kc < 32; kc += 2) {
                bf16x8 a0, a1;
                if (n < 4) {
                    a0 = *(const bf16x8*)(y_lds + n * 1032 + kc * 32 + q * 8);
                    a1 = *(const bf16x8*)(y_lds + n * 1032 + (kc + 1) * 32 + q * 8);
                } else { a0 = (bf16x8)0; a1 = (bf16x8)0; }
                acc0 = __builtin_amdgcn_mfma_f32_16x16x32_bf16(a0, wrf[kc],     acc0, 0, 0, 0);
                acc1 = __builtin_amdgcn_mfma_f32_16x16x32_bf16(a1, wrf[kc + 1], acc1, 0, 0, 0);
            }
        }

        // h update (lanes>=16 compute phantom rows; never stored, A-rows forced zero so harmless)
#pragma unroll
        for (int rr = 0; rr < 4; ++rr) {
            float rv = acc0[rr] + acc1[rr];
            h[rr] = 0.95f * h[rr] + 0.05f * (rv + ipv[rr] + biasv);
        }

        // fire y stores first (consumers are waiting on these), then hout (kernel-boundary
        // visibility). NO waits on the producer side.
        if (lane < 16) {
            char* ydst = (t < 256) ? (ybase0 + (size_t)t * 131072) : (ybase3 + (size_t)(t - 256) * 131072);
            unsigned short* yp = (unsigned short*)ydst;
#pragma unroll
            for (int rr = 0; rr < 4; ++rr) {
                unsigned short yb = f2bf(fast_tanh(h[rr]));
                __hip_atomic_store(yp + (b0 + rr) * 1024 + col, yb,
                                   __ATOMIC_RELAXED, __HIP_MEMORY_SCOPE_AGENT);
            }
#pragma unroll
            for (int rr = 0; rr < 4; ++rr)
                __builtin_nontemporal_store(h[rr], hout + ((size_t)(b0 + rr) * 512 + t) * 1024 + col);
        }
        // one barrier per step: all waves done reading y_lds before next step's staging writes
        __syncthreads();
    }
}

// ---------------------------------------------------------------------------
// Phase C: rnn_out = tanh(out2) (32768r x 1024k) @ Wout -> out3[R*256+n] and out0[(t*64+b)*256+n]
// ---------------------------------------------------------------------------
__launch_bounds__(256, 1)
__global__ void out_proj_kernel(const float* __restrict__ h, const unsigned short* __restrict__ woutT,
                                float* __restrict__ out0, float* __restrict__ out3)
{
    extern __shared__ short lds[];      // [256 n][136] bf16 per k-block
    const int tid = threadIdx.x;
    const int lane = tid & 63, wv = tid >> 6;
    const int R0 = blockIdx.x * 64;
    const int n = lane & 15, q = lane >> 4;
    f32x4 acc[16] = {};

    for (int kb = 0; kb < 8; ++kb) {
        { // stage WoutT block, coalesced + conflict-free
            const int* src = (const int*)woutT;   // [256][512 dwords]
            int* dstl = (int*)lds;                // pitch 68 dwords
#pragma unroll
            for (int it = 0; it < 64; ++it) {
                int flat = it * 256 + tid;
                int nn = flat >> 6, kd = flat & 63;
                dstl[nn * 68 + kd] = src[(size_t)nn * 512 + kb * 64 + kd];
            }
        }
        __syncthreads();

        const int row = R0 + wv * 16 + n;
#pragma unroll
        for (int kc = 0; kc < 4; ++kc) {
            int k = kb * 128 + kc * 32 + q * 8;
            const float* hp = h + (size_t)row * 1024 + k;
            union { bf16x8 v; unsigned short u[8]; } af;
#pragma unroll
            for (int jj = 0; jj < 8; ++jj) af.u[jj] = f2bf(fast_tanh(hp[jj]));
#pragma unroll
            for (int u2 = 0; u2 < 16; ++u2) {
                bf16x8 bfv = *(const bf16x8*)(lds + (u2 * 16 + n) * 136 + kc * 32 + q * 8);
                acc[u2] = __builtin_amdgcn_mfma_f32_16x16x32_bf16(af.v, bfv, acc[u2], 0, 0, 0);
            }
        }
        __syncthreads();
    }
#pragma unroll
    for (int u2 = 0; u2 < 16; ++u2) {
        int ncol = u2 * 16 + n;
#pragma unroll
        for (int rr = 0; rr < 4; ++rr) {
            int R = R0 + wv * 16 + q * 4 + rr;
            int b = R >> 9, t = R & 511;
            float v = acc[u2][rr];
            out3[(size_t)R * 256 + ncol] = v;
            out0[((size_t)t * 64 + b) * 256 + ncol] = v;
        }
    }
}

// ---------------------------------------------------------------------------
extern "C" void kernel_launch(void* const* d_in, const int* in_sizes, int n_in,
                              void* d_out, int out_size, void* d_ws, size_t ws_size,
                              hipStream_t stream)
{
    const float* x    = (const float*)d_in[0];
    const float* Win  = (const float*)d_in[1];
    const float* Wr   = (const float*)d_in[2];
    const float* bias = (const float*)d_in[3];
    const float* Wout = (const float*)d_in[4];
    float* out = (float*)d_out;
    float* o0 = out;
    float* o1 = out + O1_OFF;
    float* o2 = out + O2_OFF;
    float* o3 = out + O3_OFF;

    // ws layout: [0,+512K) winT, then woutT. (No flags: sync is data-as-flag.)
    unsigned short* winT  = (unsigned short*)d_ws;
    unsigned short* woutT = (unsigned short*)((char*)d_ws + 524288);

    hipFuncSetAttribute((const void*)input_proj_kernel, hipFuncAttributeMaxDynamicSharedMemorySize, 152064);
    hipFuncSetAttribute((const void*)out_proj_kernel,   hipFuncAttributeMaxDynamicSharedMemorySize, 69632);

    hipLaunchKernelGGL(poison_y, dim3(2048), dim3(256), 0, stream, (int*)o0, (int*)o3);
    hipLaunchKernelGGL(prep_transpose, dim3(128), dim3(256), 0, stream, Win, Wout, winT, woutT);
    hipLaunchKernelGGL(input_proj_kernel, dim3(256), dim3(256), 152064, stream, x, winT, o1);

    hipLaunchKernelGGL(rnn_scan, dim3(256), dim3(256), 0, stream,
                       Wr, bias, o1, o2, (char*)o0, (char*)o3);

    hipLaunchKernelGGL(out_proj_kernel, dim3(512), dim3(256), 69632, stream, o2, woutT, o0, o3);
}